// Round 2
// baseline (258.586 us; speedup 1.0000x reference)
//
#include <hip/hip_runtime.h>
#include <cstdint>
#include <cstddef>

#define IMSIZE 4096
#define HALF 15              // LINEWIDTH//2
#define SENT (-100000)       // "no line point at this major index"

// ---------------------------------------------------------------------------
// K1: build the line map. Bresenham variant from the reference has the closed
// form k_i = floor((2*dY*i + dX) / (2*dX)) (verified incl. d>=0 tie behavior),
// so all n points are computed in parallel. map[major] = minor coordinate.
// hdr[0] = steep flag, hdr[1] = smax accumulator (zeroed here).
// ---------------------------------------------------------------------------
__global__ __launch_bounds__(1024) void k_line(
    const float* __restrict__ x0p, const float* __restrict__ y0p,
    const float* __restrict__ x1p, const float* __restrict__ y1p,
    int* __restrict__ hdr, int* __restrict__ map)
{
    int t = threadIdx.x;
    for (int i = t; i < IMSIZE; i += 1024) map[i] = SENT;
    __syncthreads();

    float x0 = x0p[0], y0 = y0p[0], x1 = x1p[0], y1 = y1p[0];
    float dx = fabsf(x1 - x0), dy = fabsf(y1 - y0);
    float sx = (x1 > x0) ? 1.f : -1.f;
    float sy = (y1 > y0) ? 1.f : -1.f;
    bool steep = dy > dx;
    float a0 = steep ? y0 : x0;
    float b0 = steep ? x0 : y0;
    float dX = steep ? dy : dx;
    float dY = steep ? dx : dy;
    float sa = steep ? sy : sx;
    float sb = steep ? sx : sy;
    int n = (int)dX;

    if (t == 0) { hdr[0] = steep ? 1 : 0; hdr[1] = 0; }

    double twodY = 2.0 * (double)dY;
    double twodX = 2.0 * (double)dX;
    double ddX   = (double)dX;
    for (int i = t; i < n; i += 1024) {
        int ki = (int)floor((twodY * (double)i + ddX) / twodX);
        float ai = a0 + sa * (float)i;
        float bi = b0 + sb * (float)ki;
        int M  = (int)ai;
        int mn = (int)bi;
        if ((unsigned)M < IMSIZE) map[M] = mn;   // distinct M per i — no race
    }
    if (t == 0) {  // endpoint: mask[x1, y1] = 1
        int M  = steep ? (int)y1 : (int)x1;
        int mn = steep ? (int)x1 : (int)y1;
        if ((unsigned)M < IMSIZE) map[M] = mn;   // major index distinct from i<n points
    }
}

// ---------------------------------------------------------------------------
// K2: per major index M, band interval [lo,hi] in the minor axis (bounding
// interval of the 31-row window), integer conv s over band pixels,
// wave-reduce max, atomicMax into hdr[1]. One wave per major index.
// ---------------------------------------------------------------------------
__global__ __launch_bounds__(64) void k_band(
    int* __restrict__ hdr, const int* __restrict__ map,
    int* __restrict__ lo, int* __restrict__ hi)
{
    int M = blockIdx.x;
    int t = threadIdx.x;

    int v = SENT;
    if (t < 2 * HALF + 1) {
        int m = M - HALF + t;
        if ((unsigned)m < IMSIZE) v = map[m];
    }
    int vmin = (v <= SENT / 2) ? 0x7fffffff : v;
    int vmax = (v <= SENT / 2) ? (-0x7fffffff - 1) : v;
    #pragma unroll
    for (int o = 32; o >= 1; o >>= 1) {
        vmin = min(vmin, __shfl_xor(vmin, o));
        vmax = max(vmax, __shfl_xor(vmax, o));
    }
    int L, H;
    if (vmin == 0x7fffffff) { L = 1; H = 0; }           // empty band
    else { L = max(vmin - HALF, 0); H = min(vmax + HALF, IMSIZE - 1); }
    if (t == 0) { lo[M] = L; hi[M] = H; }

    int smax = 0;
    for (int j = L + t; j <= H; j += 64) {              // width <= 61, one pass
        int s = 0;
        #pragma unroll
        for (int dm = -HALF; dm <= HALF; ++dm) {
            int m = M + dm;
            if ((unsigned)m < IMSIZE) {
                int c = map[m];                          // SENT -> ad huge -> skip
                int ad = abs(c - j);
                if (ad <= HALF) s += 16 - max(ad, (dm < 0 ? -dm : dm));
            }
        }
        smax = max(smax, s);
    }
    #pragma unroll
    for (int o = 32; o >= 1; o >>= 1) smax = max(smax, __shfl_xor(smax, o));
    if (t == 0 && smax > 0) atomicMax(hdr + 1, smax);
}

// ---------------------------------------------------------------------------
// K3: write full output, 3 identical channels, float4 stores. 1.0 outside the
// band; 1 - s/smax inside (integer conv recomputed; the 3/16 kernel factor
// cancels in the min/max normalization, tmin = 0 since conv>=0 & band sparse).
// ---------------------------------------------------------------------------
__device__ __forceinline__ int conv_s(int i, int j, int steep,
                                      const int* __restrict__ map)
{
    int M  = steep ? j : i;
    int mn = steep ? i : j;
    int s = 0;
    #pragma unroll
    for (int dm = -HALF; dm <= HALF; ++dm) {
        int m = M + dm;
        if ((unsigned)m < IMSIZE) {
            int c = map[m];
            int ad = abs(c - mn);
            if (ad <= HALF) s += 16 - max(ad, (dm < 0 ? -dm : dm));
        }
    }
    return s;
}

__global__ __launch_bounds__(256) void k_write(
    const int* __restrict__ hdr, const int* __restrict__ map,
    const int* __restrict__ lo, const int* __restrict__ hi,
    float* __restrict__ out)
{
    int idx = blockIdx.x * 256 + threadIdx.x;   // 0 .. 4096*1024-1 (float4 id)
    int i  = idx >> 10;                         // row
    int j0 = (idx & 1023) << 2;                 // first col of the float4
    int steep = hdr[0];
    float inv = 1.0f / (float)hdr[1];

    float4 v = make_float4(1.f, 1.f, 1.f, 1.f);
    float* vp = &v.x;
    if (!steep) {
        int L = lo[i], H = hi[i];               // uniform per block (4 blocks/row)
        if (j0 <= H && j0 + 3 >= L) {
            #pragma unroll
            for (int k = 0; k < 4; ++k) {
                int j = j0 + k;
                if (j >= L && j <= H) {
                    int s = conv_s(i, j, 0, map);
                    vp[k] = 1.0f - (float)s * inv;
                }
            }
        }
    } else {
        #pragma unroll
        for (int k = 0; k < 4; ++k) {
            int j = j0 + k;
            if (i >= lo[j] && i <= hi[j]) {
                int s = conv_s(i, j, 1, map);
                vp[k] = 1.0f - (float)s * inv;
            }
        }
    }

    const size_t CH4 = (size_t)IMSIZE * IMSIZE / 4;   // float4s per channel
    float4* o = (float4*)out;
    o[idx]            = v;
    o[idx + CH4]      = v;
    o[idx + 2 * CH4]  = v;
}

// ---------------------------------------------------------------------------
extern "C" void kernel_launch(void* const* d_in, const int* in_sizes, int n_in,
                              void* d_out, int out_size, void* d_ws, size_t ws_size,
                              hipStream_t stream)
{
    const float* x0 = (const float*)d_in[0];
    const float* y0 = (const float*)d_in[1];
    const float* x1 = (const float*)d_in[2];
    const float* y1 = (const float*)d_in[3];

    int* ws  = (int*)d_ws;
    int* hdr = ws;                     // [0]=steep, [1]=smax
    int* map = ws + 16;                // 4096 ints
    int* lo  = ws + 16 + IMSIZE;       // 4096 ints
    int* hi  = ws + 16 + 2 * IMSIZE;   // 4096 ints
    float* out = (float*)d_out;

    hipLaunchKernelGGL(k_line,  dim3(1),                   dim3(1024), 0, stream,
                       x0, y0, x1, y1, hdr, map);
    hipLaunchKernelGGL(k_band,  dim3(IMSIZE),              dim3(64),   0, stream,
                       hdr, map, lo, hi);
    hipLaunchKernelGGL(k_write, dim3(IMSIZE * 1024 / 256), dim3(256),  0, stream,
                       hdr, map, lo, hi, out);
}

// Round 3
// 250.735 us; speedup vs baseline: 1.0313x; 1.0313x over previous
//
#include <hip/hip_runtime.h>
#include <cstdint>
#include <cstddef>

#define IMSIZE 4096
#define HALF 15              // LINEWIDTH//2
#define SENT (-100000)       // "no line point at this major index"

// ---------------------------------------------------------------------------
// K1: build the line map. The reference's Bresenham variant has the closed
// form k_i = floor((2*dY*i + dX) / (2*dX)) (verified incl. the d>=0 tie),
// so all n points are computed in parallel. map[major] = minor coordinate.
// hdr[0] = steep flag, hdr[1] = smax accumulator (zeroed here).
// ---------------------------------------------------------------------------
__global__ __launch_bounds__(1024) void k_line(
    const float* __restrict__ x0p, const float* __restrict__ y0p,
    const float* __restrict__ x1p, const float* __restrict__ y1p,
    int* __restrict__ hdr, int* __restrict__ map)
{
    int t = threadIdx.x;
    for (int i = t; i < IMSIZE; i += 1024) map[i] = SENT;
    __syncthreads();

    float x0 = x0p[0], y0 = y0p[0], x1 = x1p[0], y1 = y1p[0];
    float dx = fabsf(x1 - x0), dy = fabsf(y1 - y0);
    float sx = (x1 > x0) ? 1.f : -1.f;
    float sy = (y1 > y0) ? 1.f : -1.f;
    bool steep = dy > dx;
    float a0 = steep ? y0 : x0;
    float b0 = steep ? x0 : y0;
    float dX = steep ? dy : dx;
    float dY = steep ? dx : dy;
    float sa = steep ? sy : sx;
    float sb = steep ? sx : sy;
    int n = (int)dX;

    if (t == 0) { hdr[0] = steep ? 1 : 0; hdr[1] = 0; }

    double twodY = 2.0 * (double)dY;
    double twodX = 2.0 * (double)dX;
    double ddX   = (double)dX;
    for (int i = t; i < n; i += 1024) {
        int ki = (int)floor((twodY * (double)i + ddX) / twodX);
        float ai = a0 + sa * (float)i;
        float bi = b0 + sb * (float)ki;
        int M  = (int)ai;
        int mn = (int)bi;
        if ((unsigned)M < IMSIZE) map[M] = mn;   // distinct M per i — no race
    }
    if (t == 0) {  // endpoint: mask[x1, y1] = 1  (mask rows index x, cols y)
        int M  = steep ? (int)y1 : (int)x1;
        int mn = steep ? (int)x1 : (int)y1;
        if ((unsigned)M < IMSIZE) map[M] = mn;
    }
}

// ---------------------------------------------------------------------------
// shared helper: integer conv weight sum at pixel (row i, col j).
// mask[x=row][y=col]; map is indexed by the major axis.
// ---------------------------------------------------------------------------
__device__ __forceinline__ int conv_s(int i, int j, int steep,
                                      const int* __restrict__ map)
{
    int M  = steep ? j : i;
    int mn = steep ? i : j;
    int s = 0;
    #pragma unroll
    for (int dm = -HALF; dm <= HALF; ++dm) {
        int m = M + dm;
        if ((unsigned)m < IMSIZE) {
            int c = map[m];                 // SENT -> |c-mn| huge -> skipped
            int ad = abs(c - mn);
            if (ad <= HALF) s += 16 - max(ad, (dm < 0 ? -dm : dm));
        }
    }
    return s;
}

// ---------------------------------------------------------------------------
// K2: per major index M, band interval [lo,hi] in the minor axis, integer
// conv s over band pixels, wave-reduce max, atomicMax into hdr[1].
// ---------------------------------------------------------------------------
__global__ __launch_bounds__(64) void k_band(
    int* __restrict__ hdr, const int* __restrict__ map,
    int* __restrict__ lo, int* __restrict__ hi)
{
    int M = blockIdx.x;
    int t = threadIdx.x;

    int v = SENT;
    if (t < 2 * HALF + 1) {
        int m = M - HALF + t;
        if ((unsigned)m < IMSIZE) v = map[m];
    }
    int vmin = (v <= SENT / 2) ? 0x7fffffff : v;
    int vmax = (v <= SENT / 2) ? (-0x7fffffff - 1) : v;
    #pragma unroll
    for (int o = 32; o >= 1; o >>= 1) {
        vmin = min(vmin, __shfl_xor(vmin, o));
        vmax = max(vmax, __shfl_xor(vmax, o));
    }
    int L, H;
    if (vmin == 0x7fffffff) { L = 1; H = 0; }           // empty band
    else { L = max(vmin - HALF, 0); H = min(vmax + HALF, IMSIZE - 1); }
    if (t == 0) { lo[M] = L; hi[M] = H; }

    int steep = hdr[0];
    int smax = 0;
    for (int j = L + t; j <= H; j += 64) {              // width <= 61
        int row = steep ? j : M;
        int col = steep ? M : j;
        smax = max(smax, conv_s(row, col, steep, map));
    }
    #pragma unroll
    for (int o = 32; o >= 1; o >>= 1) smax = max(smax, __shfl_xor(smax, o));
    if (t == 0 && smax > 0) atomicMax(hdr + 1, smax);
}

// ---------------------------------------------------------------------------
// K3: pure streaming fill — every output element := 1.0f. Structurally
// identical to the harness memset (float4/lane, linear) → memset-rate BW.
// ---------------------------------------------------------------------------
__global__ __launch_bounds__(256) void k_fill(float4* __restrict__ out)
{
    size_t idx = (size_t)blockIdx.x * 256 + threadIdx.x;
    out[idx] = make_float4(1.f, 1.f, 1.f, 1.f);
}

// ---------------------------------------------------------------------------
// K4: patch only the band pixels (~61 per major index, x3 channels ~ 3 MB).
// ---------------------------------------------------------------------------
__global__ __launch_bounds__(64) void k_patch(
    const int* __restrict__ hdr, const int* __restrict__ map,
    const int* __restrict__ lo, const int* __restrict__ hi,
    float* __restrict__ out)
{
    int M = blockIdx.x;
    int t = threadIdx.x;
    int L = lo[M], H = hi[M];
    int steep = hdr[0];
    float inv = 1.0f / (float)hdr[1];
    const size_t CH = (size_t)IMSIZE * IMSIZE;

    for (int j = L + t; j <= H; j += 64) {              // width <= 61
        int row = steep ? j : M;
        int col = steep ? M : j;
        int s = conv_s(row, col, steep, map);
        float val = 1.0f - (float)s * inv;
        size_t p = (size_t)row * IMSIZE + col;
        out[p]          = val;
        out[p + CH]     = val;
        out[p + 2 * CH] = val;
    }
}

// ---------------------------------------------------------------------------
extern "C" void kernel_launch(void* const* d_in, const int* in_sizes, int n_in,
                              void* d_out, int out_size, void* d_ws, size_t ws_size,
                              hipStream_t stream)
{
    const float* x0 = (const float*)d_in[0];
    const float* y0 = (const float*)d_in[1];
    const float* x1 = (const float*)d_in[2];
    const float* y1 = (const float*)d_in[3];

    int* ws  = (int*)d_ws;
    int* hdr = ws;                     // [0]=steep, [1]=smax
    int* map = ws + 16;                // 4096 ints
    int* lo  = ws + 16 + IMSIZE;       // 4096 ints
    int* hi  = ws + 16 + 2 * IMSIZE;   // 4096 ints
    float* out = (float*)d_out;

    const int NF4 = 3 * IMSIZE * IMSIZE / 4;           // float4 count

    hipLaunchKernelGGL(k_fill,  dim3(NF4 / 256), dim3(256),  0, stream,
                       (float4*)out);
    hipLaunchKernelGGL(k_line,  dim3(1),         dim3(1024), 0, stream,
                       x0, y0, x1, y1, hdr, map);
    hipLaunchKernelGGL(k_band,  dim3(IMSIZE),    dim3(64),   0, stream,
                       hdr, map, lo, hi);
    hipLaunchKernelGGL(k_patch, dim3(IMSIZE),    dim3(64),   0, stream,
                       hdr, map, lo, hi, out);
}